// Round 1
// baseline (626.743 us; speedup 1.0000x reference)
//
#include <hip/hip_runtime.h>

#define N 8192
#define T 64
#define TILES (N / T)                      // 128
#define NPAIRS (TILES * (TILES + 1) / 2)   // 8256
#define LDS_STRIDE 65                      // +1 pad: transposed reads are 2-way (free)

// Decode linear pair index p -> (bi <= bj), upper triangle incl. diagonal.
// offset(bi) = bi*TILES - bi*(bi-1)/2
__device__ inline void decode_pair(int p, int& bi, int& bj) {
    float t = (float)TILES + 0.5f;
    int g = (int)(t - sqrtf(t * t - 2.0f * (float)p));
    if (g < 0) g = 0;
    if (g > TILES - 1) g = TILES - 1;
    while (g < TILES - 1 && ((g + 1) * TILES - (g + 1) * g / 2) <= p) g++;
    while (g > 0 && (g * TILES - g * (g - 1) / 2) > p) g--;
    bi = g;
    bj = bi + (p - (bi * TILES - bi * (bi - 1) / 2));
}

// Coalesced float4 load of a 64x64 tile into LDS (scalar stores, stride 65).
__device__ inline void load_tile(const float* __restrict__ src, int row0, int col0,
                                 float* lds) {
    int t = threadIdx.x;
    int c4 = t & 15;        // float4 column 0..15
    int r0 = t >> 4;        // row 0..15
    #pragma unroll
    for (int rr = r0; rr < T; rr += 16) {
        const float4 v = *(const float4*)(src + (size_t)(row0 + rr) * N + col0 + c4 * 4);
        float* d = lds + rr * LDS_STRIDE + c4 * 4;
        d[0] = v.x; d[1] = v.y; d[2] = v.z; d[3] = v.w;
    }
}

// Pass 1: rowsum[i] = sum_j max(adj[i][j], adj[j][i]), diagonal term = 1.
__global__ __launch_bounds__(256) void k_rowsum(const float* __restrict__ adj,
                                                float* __restrict__ rowsum) {
    __shared__ float ldsA[T * LDS_STRIDE];
    __shared__ float ldsB[T * LDS_STRIDE];
    int bi, bj;
    decode_pair((int)blockIdx.x, bi, bj);

    load_tile(adj, bi * T, bj * T, ldsA);   // A = adj[bi-rows, bj-cols]
    load_tile(adj, bj * T, bi * T, ldsB);   // B = adj[bj-rows, bi-cols]
    __syncthreads();

    int t = threadIdx.x;
    int c = t & 63;     // column within tile
    int w = t >> 6;     // wave id 0..3
    float colacc = 0.0f;
    for (int r = w; r < T; r += 4) {
        // M[r][c] = max(A[r][c], B[c][r]) = symmetrized element (bi*T+r, bj*T+c)
        float m = fmaxf(ldsA[r * LDS_STRIDE + c], ldsB[c * LDS_STRIDE + r]);
        if (bi == bj && r == c) m = 1.0f;   // self-loop
        colacc += m;
        // row sum across the wave's 64 lanes (all lanes share r)
        float rs = m;
        #pragma unroll
        for (int off = 32; off > 0; off >>= 1) rs += __shfl_down(rs, off);
        if (c == 0) atomicAdd(&rowsum[bi * T + r], rs);
    }
    // column sums of M are row sums for the bj-block rows (skip on diag tile:
    // already fully counted by the row pass)
    if (bi != bj) atomicAdd(&rowsum[bj * T + c], colacc);
}

// Pass 2: out[i][j] = max'(i,j) * rsqrt(rowsum[i]) * rsqrt(rowsum[j])
__global__ __launch_bounds__(256) void k_scale(const float* __restrict__ adj,
                                               const float* __restrict__ rowsum,
                                               float* __restrict__ out) {
    __shared__ float ldsA[T * LDS_STRIDE];
    __shared__ float ldsB[T * LDS_STRIDE];
    __shared__ float dinvA[T];
    __shared__ float dinvB[T];
    int bi, bj;
    decode_pair((int)blockIdx.x, bi, bj);

    int t = threadIdx.x;
    if (t < 64)       dinvA[t]      = rsqrtf(rowsum[bi * T + t]);
    else if (t < 128) dinvB[t - 64] = rsqrtf(rowsum[bj * T + (t - 64)]);
    load_tile(adj, bi * T, bj * T, ldsA);
    load_tile(adj, bj * T, bi * T, ldsB);
    __syncthreads();

    int c4 = t & 15;
    int r0 = t >> 4;
    // Upper tile: rows bi*T+rr, cols bj*T+cc — coalesced float4 stores
    #pragma unroll
    for (int rr = r0; rr < T; rr += 16) {
        float4 v;
        float* vp = &v.x;
        #pragma unroll
        for (int k = 0; k < 4; k++) {
            int cc = c4 * 4 + k;
            float m = fmaxf(ldsA[rr * LDS_STRIDE + cc], ldsB[cc * LDS_STRIDE + rr]);
            if (bi == bj && rr == cc) m = 1.0f;
            vp[k] = m * dinvA[rr] * dinvB[cc];
        }
        *(float4*)(out + (size_t)(bi * T + rr) * N + bj * T + c4 * 4) = v;
    }
    // Mirror tile: rows bj*T+rr, cols bi*T+cc
    if (bi != bj) {
        #pragma unroll
        for (int rr = r0; rr < T; rr += 16) {
            float4 v;
            float* vp = &v.x;
            #pragma unroll
            for (int k = 0; k < 4; k++) {
                int cc = c4 * 4 + k;
                float m = fmaxf(ldsB[rr * LDS_STRIDE + cc], ldsA[cc * LDS_STRIDE + rr]);
                vp[k] = m * dinvB[rr] * dinvA[cc];
            }
            *(float4*)(out + (size_t)(bj * T + rr) * N + bi * T + c4 * 4) = v;
        }
    }
}

extern "C" void kernel_launch(void* const* d_in, const int* in_sizes, int n_in,
                              void* d_out, int out_size, void* d_ws, size_t ws_size,
                              hipStream_t stream) {
    const float* adj = (const float*)d_in[0];
    float* out = (float*)d_out;
    float* rowsum = (float*)d_ws;   // N floats of scratch

    hipMemsetAsync(rowsum, 0, N * sizeof(float), stream);
    k_rowsum<<<NPAIRS, 256, 0, stream>>>(adj, rowsum);
    k_scale<<<NPAIRS, 256, 0, stream>>>(adj, rowsum, out);
}

// Round 2
// 503.205 us; speedup vs baseline: 1.2455x; 1.2455x over previous
//
#include <hip/hip_runtime.h>

#define N 8192
#define T 64
#define TILES (N / T)                      // 128
#define NPAIRS (TILES * (TILES + 1) / 2)   // 8256
#define LDS_STRIDE 65                      // +1 pad: transposed reads are 2-way (free per m136)
#define BLOCK 512

// Decode linear pair index p -> (bi <= bj), upper triangle incl. diagonal.
__device__ inline void decode_pair(int p, int& bi, int& bj) {
    float t = (float)TILES + 0.5f;
    int g = (int)(t - sqrtf(t * t - 2.0f * (float)p));
    if (g < 0) g = 0;
    if (g > TILES - 1) g = TILES - 1;
    while (g < TILES - 1 && ((g + 1) * TILES - (g + 1) * g / 2) <= p) g++;
    while (g > 0 && (g * TILES - g * (g - 1) / 2) > p) g--;
    bi = g;
    bj = bi + (p - (bi * TILES - bi * (bi - 1) / 2));
}

// Coalesced float4 load of a 64x64 tile into LDS (512 threads: 2 iterations).
__device__ inline void load_tile(const float* __restrict__ src, int row0, int col0,
                                 float* lds) {
    int t = threadIdx.x;
    int c4 = t & 15;        // float4 column 0..15
    int r0 = t >> 4;        // row 0..31
    #pragma unroll
    for (int rr = r0; rr < T; rr += 32) {
        const float4 v = *(const float4*)(src + (size_t)(row0 + rr) * N + col0 + c4 * 4);
        float* d = lds + rr * LDS_STRIDE + c4 * 4;
        d[0] = v.x; d[1] = v.y; d[2] = v.z; d[3] = v.w;
    }
}

// Pass 1: rowsum[i] = sum_j max(adj[i][j], adj[j][i]), diagonal forced to 1.
// No shuffles: per-thread 8-element accumulation + LDS tree + 1 atomic per row.
__global__ __launch_bounds__(BLOCK) void k_rowsum(const float* __restrict__ adj,
                                                  float* __restrict__ rowsum) {
    __shared__ float ldsA[T * LDS_STRIDE];
    __shared__ float ldsB[T * LDS_STRIDE];
    __shared__ float red[BLOCK];
    int bi, bj;
    decode_pair((int)blockIdx.x, bi, bj);

    load_tile(adj, bi * T, bj * T, ldsA);   // A = adj[bi-rows, bj-cols]
    load_tile(adj, bj * T, bi * T, ldsB);   // B = adj[bj-rows, bi-cols]
    __syncthreads();

    int t = threadIdx.x;
    int lane = t & 63;
    int w = t >> 6;         // 0..7

    // Row sums for bi-block rows: thread owns row r=lane, cols w*8..w*8+7.
    // ldsA read: stride-65 across lanes (2-way, free); ldsB read: consecutive (free).
    float acc = 0.0f;
    #pragma unroll
    for (int k = 0; k < 8; k++) {
        int c = w * 8 + k;
        float m = fmaxf(ldsA[lane * LDS_STRIDE + c], ldsB[c * LDS_STRIDE + lane]);
        if (bi == bj && lane == c) m = 1.0f;   // self-loop
        acc += m;
    }
    red[t] = acc;
    __syncthreads();
    if (t < 64) {
        float s = 0.0f;
        #pragma unroll
        for (int w2 = 0; w2 < 8; w2++) s += red[w2 * 64 + t];
        atomicAdd(&rowsum[bi * T + t], s);
    }

    // Column sums of M = row sums for bj-block rows (off-diag tiles only;
    // diag tile already fully counted above).
    if (bi != bj) {
        __syncthreads();
        float acc2 = 0.0f;
        #pragma unroll
        for (int k = 0; k < 8; k++) {
            int r = w * 8 + k;
            acc2 += fmaxf(ldsA[r * LDS_STRIDE + lane], ldsB[lane * LDS_STRIDE + r]);
        }
        red[t] = acc2;
        __syncthreads();
        if (t < 64) {
            float s = 0.0f;
            #pragma unroll
            for (int w2 = 0; w2 < 8; w2++) s += red[w2 * 64 + t];
            atomicAdd(&rowsum[bj * T + t], s);
        }
    }
}

// Pass 2: out[i][j] = max'(i,j) * rsqrt(rowsum[i]) * rsqrt(rowsum[j])
__global__ __launch_bounds__(BLOCK) void k_scale(const float* __restrict__ adj,
                                                 const float* __restrict__ rowsum,
                                                 float* __restrict__ out) {
    __shared__ float ldsA[T * LDS_STRIDE];
    __shared__ float ldsB[T * LDS_STRIDE];
    __shared__ float dinvA[T];
    __shared__ float dinvB[T];
    int bi, bj;
    decode_pair((int)blockIdx.x, bi, bj);

    int t = threadIdx.x;
    if (t < 64)       dinvA[t]      = rsqrtf(rowsum[bi * T + t]);
    else if (t < 128) dinvB[t - 64] = rsqrtf(rowsum[bj * T + (t - 64)]);
    load_tile(adj, bi * T, bj * T, ldsA);
    load_tile(adj, bj * T, bi * T, ldsB);
    __syncthreads();

    int c4 = t & 15;
    int r0 = t >> 4;    // 0..31
    // Upper tile: rows bi*T+rr, cols bj*T+cc — coalesced float4 stores
    #pragma unroll
    for (int rr = r0; rr < T; rr += 32) {
        float4 v;
        float* vp = &v.x;
        #pragma unroll
        for (int k = 0; k < 4; k++) {
            int cc = c4 * 4 + k;
            float m = fmaxf(ldsA[rr * LDS_STRIDE + cc], ldsB[cc * LDS_STRIDE + rr]);
            if (bi == bj && rr == cc) m = 1.0f;
            vp[k] = m * dinvA[rr] * dinvB[cc];
        }
        *(float4*)(out + (size_t)(bi * T + rr) * N + bj * T + c4 * 4) = v;
    }
    // Mirror tile: rows bj*T+rr, cols bi*T+cc
    if (bi != bj) {
        #pragma unroll
        for (int rr = r0; rr < T; rr += 32) {
            float4 v;
            float* vp = &v.x;
            #pragma unroll
            for (int k = 0; k < 4; k++) {
                int cc = c4 * 4 + k;
                float m = fmaxf(ldsB[rr * LDS_STRIDE + cc], ldsA[cc * LDS_STRIDE + rr]);
                vp[k] = m * dinvB[rr] * dinvA[cc];
            }
            *(float4*)(out + (size_t)(bj * T + rr) * N + bi * T + c4 * 4) = v;
        }
    }
}

extern "C" void kernel_launch(void* const* d_in, const int* in_sizes, int n_in,
                              void* d_out, int out_size, void* d_ws, size_t ws_size,
                              hipStream_t stream) {
    const float* adj = (const float*)d_in[0];
    float* out = (float*)d_out;
    float* rowsum = (float*)d_ws;   // N floats of scratch

    hipMemsetAsync(rowsum, 0, N * sizeof(float), stream);
    k_rowsum<<<NPAIRS, BLOCK, 0, stream>>>(adj, rowsum);
    k_scale<<<NPAIRS, BLOCK, 0, stream>>>(adj, rowsum, out);
}